// Round 2
// baseline (376.664 us; speedup 1.0000x reference)
//
#include <hip/hip_runtime.h>
#include <hip/hip_bf16.h>
#include <math.h>

// PillarHist: per-row 64-bin hist (count/mean_z/mean_r, bin-interleaved) -> Linear(192->64) -> BN(train) -> ReLU
// k1: wave-private LDS hist (no block barriers) + bf16 MFMA GEMM (B in registers) + BN partial atomics
// k2: 64-thread scale/shift from totals.  k3: apply BN+ReLU in-place (float4).

typedef __attribute__((ext_vector_type(8))) short bf16x8;   // 8 bf16 in 4 VGPRs
typedef __attribute__((ext_vector_type(4))) float f32x4;

#define ZMINF   (-3.0f)
#define INV_BIN 16.0f        // 1/BIN_SIZE, exact pow2
#define HROWS   16           // rows per wave (MFMA M)
#define HPAD    196          // padded hist row stride (floats); 196%8==4 -> conflict-free b128 A-reads

__device__ __forceinline__ short f2bf(float f) {
    __hip_bfloat16 h = __float2bfloat16(f);   // RNE
    return __builtin_bit_cast(short, h);
}

__global__ __launch_bounds__(256, 3)
void k1_hist_mfma(const float4* __restrict__ feat,   // [M,64] float4 (C=4)
                  const int*    __restrict__ nump,   // [M]
                  const float*  __restrict__ W,      // [64,192] row-major (channel-major)
                  const float*  __restrict__ bvec,   // [64]
                  float*        __restrict__ xout,   // [M,64] pre-BN x (d_out)
                  float*        __restrict__ totals, // [128] global atomics: sum | sumsq
                  int M)
{
    __shared__ float sH[4 * HROWS * HPAD];   // 50176 B: wave-private hist regions

    const int tid  = threadIdx.x;
    const int wave = tid >> 6;
    const int lane = tid & 63;
    const int col  = lane & 15;   // MFMA n / m index
    const int quad = lane >> 4;

    // ---- B fragments in registers: bF[kstep][ntile], B[k][n] = W[n][perm(k)] as bf16 ----
    // planar k: [0,64)=count, [64,128)=sum_z->mean_z, [128,192)=sum_r->mean_r
    // reference hist column for planar k: k<64 -> 3k ; k<128 -> 3(k-64)+1 ; else 3(k-128)+2
    bf16x8 bF[6][4];
    #pragma unroll
    for (int s = 0; s < 6; ++s) {
        #pragma unroll
        for (int t = 0; t < 4; ++t) {
            const int  nn = t * 16 + col;
            const int  kb = s * 32 + quad * 8;
            const float* wr = W + nn * 192;
            bf16x8 f;
            #pragma unroll
            for (int j = 0; j < 8; ++j) {
                const int gk = kb + j;
                const int wc = (gk < 64) ? 3 * gk
                             : (gk < 128) ? 3 * (gk - 64) + 1
                                          : 3 * (gk - 128) + 2;
                f[j] = f2bf(wr[wc]);
            }
            bF[s][t] = f;
        }
    }

    const int gbase = (blockIdx.x * 4 + wave) * HROWS;
    float* hw = &sH[wave * HROWS * HPAD];
    float psum[4] = {0.f, 0.f, 0.f, 0.f};
    float psq[4]  = {0.f, 0.f, 0.f, 0.f};

    if (gbase < M) {
        // ---- zero hist region (wave-private; DS pipe is in-order per wave) ----
        {
            float4 z4 = {0.f, 0.f, 0.f, 0.f};
            float4* p4 = (float4*)hw;
            #pragma unroll
            for (int i = 0; i < 13; ++i) {
                const int idx = lane + i * 64;
                if (idx < (HROWS * HPAD) / 4) p4[idx] = z4;
            }
        }
        __builtin_amdgcn_wave_barrier();

        // ---- build 16 rows, planar layout [count|sum_z|sum_r], no barriers ----
        for (int r = 0; r < HROWS; ++r) {
            const int row = gbase + r;
            if (row < M) {
                const float4 v = feat[(size_t)row * 64 + lane];
                const int np = nump[row];
                if (lane < np) {
                    const float z = v.z, rr = v.w;
                    int bi = (int)((z - ZMINF) * INV_BIN);   // trunc, matches astype(int32)
                    bi = min(max(bi, 0), 63);
                    float* hrow = hw + r * HPAD;
                    atomicAdd(hrow + bi, 1.0f);
                    atomicAdd(hrow + 64 + bi, z);
                    atomicAdd(hrow + 128 + bi, rr);
                }
            }
        }
        __builtin_amdgcn_wave_barrier();
        __threadfence_block();   // drain ds_adds before fragment reads

        // ---- A-frags from LDS (2x ds_read_b128 each), means on the fly, 24 MFMAs ----
        f32x4 acc[4] = {};
        const float* ar = hw + col * HPAD + quad * 8;   // A row m = col
        float c0[8], c1[8];                              // counts -> reciprocals (reused z->r)
        #pragma unroll
        for (int s = 0; s < 6; ++s) {
            const float4* ap = (const float4*)(ar + s * 32);
            const float4 a0 = ap[0], a1 = ap[1];
            float av[8] = {a0.x, a0.y, a0.z, a0.w, a1.x, a1.y, a1.z, a1.w};
            if (s == 0) {
                #pragma unroll
                for (int j = 0; j < 8; ++j) c0[j] = av[j];
            } else if (s == 1) {
                #pragma unroll
                for (int j = 0; j < 8; ++j) c1[j] = av[j];
            } else if (s == 2) {
                #pragma unroll
                for (int j = 0; j < 8; ++j) { c0[j] = __builtin_amdgcn_rcpf(c0[j] + 1e-5f); av[j] *= c0[j]; }
            } else if (s == 3) {
                #pragma unroll
                for (int j = 0; j < 8; ++j) { c1[j] = __builtin_amdgcn_rcpf(c1[j] + 1e-5f); av[j] *= c1[j]; }
            } else if (s == 4) {
                #pragma unroll
                for (int j = 0; j < 8; ++j) av[j] *= c0[j];
            } else {
                #pragma unroll
                for (int j = 0; j < 8; ++j) av[j] *= c1[j];
            }
            bf16x8 af;
            #pragma unroll
            for (int j = 0; j < 8; ++j) af[j] = f2bf(av[j]);
            #pragma unroll
            for (int t = 0; t < 4; ++t)
                acc[t] = __builtin_amdgcn_mfma_f32_16x16x32_bf16(af, bF[s][t], acc[t], 0, 0, 0);
        }

        // ---- epilogue: +bias, store x, BN partial sums. C/D: col=lane&15, row=quad*4+i ----
        #pragma unroll
        for (int t = 0; t < 4; ++t) {
            const float bias = bvec[t * 16 + col];
            #pragma unroll
            for (int i = 0; i < 4; ++i) {
                const int row = gbase + quad * 4 + i;
                if (row < M) {
                    const float xv = acc[t][i] + bias;
                    xout[(size_t)row * 64 + t * 16 + col] = xv;
                    psum[t] += xv;
                    psq[t]  += xv * xv;
                }
            }
        }
    }

    // ---- BN partials: quad-reduce in-wave, block-reduce via LDS, one atomic set per block ----
    #pragma unroll
    for (int t = 0; t < 4; ++t) {
        psum[t] += __shfl_xor(psum[t], 16);
        psum[t] += __shfl_xor(psum[t], 32);
        psq[t]  += __shfl_xor(psq[t], 16);
        psq[t]  += __shfl_xor(psq[t], 32);
    }
    __syncthreads();               // everyone done with hist regions
    float* hw2 = &sH[wave * HROWS * HPAD];
    if (quad == 0) {
        #pragma unroll
        for (int t = 0; t < 4; ++t) {
            hw2[t * 16 + col]      = psum[t];
            hw2[64 + t * 16 + col] = psq[t];
        }
    }
    __syncthreads();
    if (tid < 128) {
        const float tot = sH[tid] + sH[HROWS * HPAD + tid]
                        + sH[2 * HROWS * HPAD + tid] + sH[3 * HROWS * HPAD + tid];
        atomicAdd(&totals[tid], tot);
    }
}

__global__ __launch_bounds__(64)
void k2_bnstats(const float* __restrict__ totals,
                const float* __restrict__ gamma,
                const float* __restrict__ beta,
                float* __restrict__ scsh, float invM)
{
    const int t = threadIdx.x;   // 64
    const float mu  = totals[t] * invM;
    const float q   = totals[64 + t] * invM;
    const float var = q - mu * mu;
    const float rstd = 1.0f / sqrtf(var + 1e-5f);
    const float a = gamma[t] * rstd;
    scsh[t]      = a;
    scsh[64 + t] = beta[t] - mu * a;
}

__global__ __launch_bounds__(256)
void k3_bn_apply(float4* __restrict__ x, const float* __restrict__ scsh, int n4)
{
    const int i = blockIdx.x * 256 + threadIdx.x;
    if (i >= n4) return;
    const float4* a4 = (const float4*)scsh;
    const float4 a = a4[i & 15];         // 64 ch = 16 float4
    const float4 c = a4[16 + (i & 15)];
    float4 v = x[i];
    v.x = fmaxf(fmaf(v.x, a.x, c.x), 0.f);
    v.y = fmaxf(fmaf(v.y, a.y, c.y), 0.f);
    v.z = fmaxf(fmaf(v.z, a.z, c.z), 0.f);
    v.w = fmaxf(fmaf(v.w, a.w, c.w), 0.f);
    x[i] = v;
}

extern "C" void kernel_launch(void* const* d_in, const int* in_sizes, int n_in,
                              void* d_out, int out_size, void* d_ws, size_t ws_size,
                              hipStream_t stream) {
    const float4* feat  = (const float4*)d_in[0];  // [M,64,4] fp32
    const int*    nump  = (const int*)d_in[1];     // [M]
    // d_in[2] = coors (unused)
    const float*  W     = (const float*)d_in[3];   // [64,192]
    const float*  bvec  = (const float*)d_in[4];   // [64]
    const float*  gamma = (const float*)d_in[5];   // [64]
    const float*  beta  = (const float*)d_in[6];   // [64]

    const int M = in_sizes[1];
    float* xout   = (float*)d_out;
    float* totals = (float*)d_ws;        // [128]
    float* scsh   = totals + 128;        // [128]

    hipMemsetAsync(d_ws, 0, 128 * sizeof(float), stream);   // zero BN accumulators

    const int nblk = (M + 4 * HROWS - 1) / (4 * HROWS);     // 64 rows/block
    k1_hist_mfma<<<nblk, 256, 0, stream>>>(feat, nump, W, bvec, xout, totals, M);
    k2_bnstats<<<1, 64, 0, stream>>>(totals, gamma, beta, scsh, 1.0f / (float)M);

    const int n4 = out_size / 4;
    k3_bn_apply<<<(n4 + 255) / 256, 256, 0, stream>>>((float4*)d_out, scsh, n4);
}

// Round 3
// 254.338 us; speedup vs baseline: 1.4810x; 1.4810x over previous
//
#include <hip/hip_runtime.h>
#include <hip/hip_bf16.h>
#include <math.h>

// PillarHist: per-row 64-bin hist (count/mean_z/mean_r interleaved) -> Linear(192->64) -> BN(train) -> ReLU
// k1: wave-private LDS hist + bf16 MFMA GEMM with B fragments in LDS (frag-major, 1x ds_read_b128 each)
//     + BN partial sums via one global atomic set per block.
// k3: recompute scale/shift from totals per block (cheap, deterministic) + apply BN+ReLU in-place.

typedef __attribute__((ext_vector_type(8))) short bf16x8;   // 8 bf16 = 4 VGPRs = 16 B
typedef __attribute__((ext_vector_type(4))) float f32x4;

#define ZMINF   (-3.0f)
#define INV_BIN 16.0f        // 1/BIN_SIZE (exact pow2)
#define HROWS   16           // rows per wave (MFMA M)
#define HPAD    196          // hist row stride (floats); bank base (4*col+8*quad)%32 -> only 2-way b128 aliasing

__device__ __forceinline__ short f2bf(float f) {
    __hip_bfloat16 h = __float2bfloat16(f);   // RNE
    return __builtin_bit_cast(short, h);
}

__global__ __launch_bounds__(256, 2)
void k1_hist_mfma(const float4* __restrict__ feat,   // [M,64] float4 (C=4)
                  const int*    __restrict__ nump,   // [M]
                  const float*  __restrict__ W,      // [64,192] row-major
                  const float*  __restrict__ bvec,   // [64]
                  float*        __restrict__ xout,   // [M,64] pre-BN x (d_out)
                  float*        __restrict__ totals, // [128] global atomics: sum | sumsq
                  int M)
{
    __shared__ float  sH[4 * HROWS * HPAD];   // 50176 B: wave-private hist regions
    __shared__ bf16x8 sWf[24 * 64];           // 24576 B: B fragments, frag-major [s*4+t][lane]

    const int tid  = threadIdx.x;
    const int wave = tid >> 6;
    const int lane = tid & 63;
    const int col  = lane & 15;
    const int quad = lane >> 4;

    // ---- stage permuted W as bf16 B-fragments (shared by all waves; no per-thread register tile) ----
    // B[k][n] = W[n][perm(k)]; planar k: [0,64)=count, [64,128)=mean_z, [128,192)=mean_r
    {
        short* sW = (short*)sWf;
        for (int e = tid; e < 24 * 64 * 8; e += 256) {
            const int j  = e & 7;
            const int ln = (e >> 3) & 63;
            const int st = e >> 9;                      // 0..23 = s*4+t
            const int s  = st >> 2, t = st & 3;
            const int k  = s * 32 + (ln >> 4) * 8 + j;
            const int n  = t * 16 + (ln & 15);
            const int wc = (k < 64) ? 3 * k
                         : (k < 128) ? 3 * (k - 64) + 1
                                     : 3 * (k - 128) + 2;
            sW[e] = f2bf(W[n * 192 + wc]);
        }
    }

    const int gbase = (blockIdx.x * 4 + wave) * HROWS;
    float* hw = &sH[wave * HROWS * HPAD];
    float psum[4] = {0.f, 0.f, 0.f, 0.f};
    float psq[4]  = {0.f, 0.f, 0.f, 0.f};

    if (gbase < M) {
        // ---- zero wave-private hist region ----
        float4* p4 = (float4*)hw;
        #pragma unroll
        for (int i = 0; i < 13; ++i) {
            const int idx = lane + i * 64;
            if (idx < (HROWS * HPAD) / 4) p4[idx] = float4{0.f, 0.f, 0.f, 0.f};
        }
        __builtin_amdgcn_wave_barrier();

        // ---- build 16 rows, 4 at a time (independent loads issued together, latencies overlap) ----
        #pragma unroll
        for (int rb = 0; rb < HROWS; rb += 4) {
            float4 v[4]; int np[4];
            #pragma unroll
            for (int u = 0; u < 4; ++u) {
                const int row = gbase + rb + u;
                const int rc  = min(row, M - 1);           // branchless clamp (np=0 kills OOB rows)
                v[u]  = feat[(size_t)rc * 64 + lane];
                np[u] = (row < M) ? nump[rc] : 0;
            }
            #pragma unroll
            for (int u = 0; u < 4; ++u) {
                if (lane < np[u]) {
                    const float z = v[u].z, rr = v[u].w;
                    int bi = (int)((z - ZMINF) * INV_BIN);  // trunc, matches astype(int32)
                    bi = min(max(bi, 0), 63);
                    float* hrow = hw + (rb + u) * HPAD;
                    atomicAdd(hrow + bi, 1.0f);
                    atomicAdd(hrow + 64 + bi, z);
                    atomicAdd(hrow + 128 + bi, rr);
                }
            }
        }
        __builtin_amdgcn_wave_barrier();
        __threadfence_block();   // drain ds_adds before fragment reads (wave-private region)
    }
    __syncthreads();             // W staging visible to all waves

    if (gbase < M) {
        // ---- A-frags from LDS, means on the fly; B-frags: one ds_read_b128 each; 24 MFMAs ----
        f32x4 acc[4] = {};
        const float* ar = hw + col * HPAD + quad * 8;   // A row m = col, k = quad*8+j (+32s)
        float c0[8], c1[8];
        #pragma unroll
        for (int s = 0; s < 6; ++s) {
            const float4* ap = (const float4*)(ar + s * 32);
            const float4 a0 = ap[0], a1 = ap[1];
            float av[8] = {a0.x, a0.y, a0.z, a0.w, a1.x, a1.y, a1.z, a1.w};
            if (s == 0) {
                #pragma unroll
                for (int j = 0; j < 8; ++j) c0[j] = av[j];
            } else if (s == 1) {
                #pragma unroll
                for (int j = 0; j < 8; ++j) c1[j] = av[j];
            } else if (s == 2) {
                #pragma unroll
                for (int j = 0; j < 8; ++j) { c0[j] = __builtin_amdgcn_rcpf(c0[j] + 1e-5f); av[j] *= c0[j]; }
            } else if (s == 3) {
                #pragma unroll
                for (int j = 0; j < 8; ++j) { c1[j] = __builtin_amdgcn_rcpf(c1[j] + 1e-5f); av[j] *= c1[j]; }
            } else if (s == 4) {
                #pragma unroll
                for (int j = 0; j < 8; ++j) av[j] *= c0[j];
            } else {
                #pragma unroll
                for (int j = 0; j < 8; ++j) av[j] *= c1[j];
            }
            bf16x8 af;
            #pragma unroll
            for (int j = 0; j < 8; ++j) af[j] = f2bf(av[j]);
            #pragma unroll
            for (int t = 0; t < 4; ++t) {
                const bf16x8 bfr = sWf[(s * 4 + t) * 64 + lane];  // conflict-free ds_read_b128
                acc[t] = __builtin_amdgcn_mfma_f32_16x16x32_bf16(af, bfr, acc[t], 0, 0, 0);
            }
        }

        // ---- epilogue: +bias, store x, BN partials. C/D: col=lane&15, row=quad*4+i ----
        #pragma unroll
        for (int t = 0; t < 4; ++t) {
            const float bias = bvec[t * 16 + col];
            #pragma unroll
            for (int i = 0; i < 4; ++i) {
                const int row = gbase + quad * 4 + i;
                if (row < M) {
                    const float xv = acc[t][i] + bias;
                    xout[(size_t)row * 64 + t * 16 + col] = xv;
                    psum[t] += xv;
                    psq[t]  += xv * xv;
                }
            }
        }
    }

    // ---- BN partials: quad-reduce in-wave, block-reduce via LDS, one atomic set per block ----
    #pragma unroll
    for (int t = 0; t < 4; ++t) {
        psum[t] += __shfl_xor(psum[t], 16);
        psum[t] += __shfl_xor(psum[t], 32);
        psq[t]  += __shfl_xor(psq[t], 16);
        psq[t]  += __shfl_xor(psq[t], 32);
    }
    __syncthreads();   // everyone done with hist regions; reuse sH
    float* hw2 = &sH[wave * HROWS * HPAD];
    if (quad == 0) {
        #pragma unroll
        for (int t = 0; t < 4; ++t) {
            hw2[t * 16 + col]      = psum[t];
            hw2[64 + t * 16 + col] = psq[t];
        }
    }
    __syncthreads();
    if (tid < 128) {
        const float tot = sH[tid] + sH[HROWS * HPAD + tid]
                        + sH[2 * HROWS * HPAD + tid] + sH[3 * HROWS * HPAD + tid];
        atomicAdd(&totals[tid], tot);
    }
}

__global__ __launch_bounds__(256)
void k3_bn_apply(float4* __restrict__ x,
                 const float* __restrict__ totals,
                 const float* __restrict__ gamma,
                 const float* __restrict__ beta,
                 float invM, int n4)
{
    __shared__ float sa[64];
    __shared__ float sc[64];
    const int t = threadIdx.x;
    if (t < 64) {   // per-block recompute of scale/shift: 512 B L2-hot, deterministic across blocks
        const float mu   = totals[t] * invM;
        const float q    = totals[64 + t] * invM;
        const float var  = q - mu * mu;
        const float rstd = 1.0f / sqrtf(var + 1e-5f);
        const float a    = gamma[t] * rstd;
        sa[t] = a;
        sc[t] = beta[t] - mu * a;
    }
    __syncthreads();
    const int i = blockIdx.x * 256 + t;
    if (i >= n4) return;
    const float4 a = ((const float4*)sa)[i & 15];   // 64 ch = 16 float4
    const float4 c = ((const float4*)sc)[i & 15];
    float4 v = x[i];
    v.x = fmaxf(fmaf(v.x, a.x, c.x), 0.f);
    v.y = fmaxf(fmaf(v.y, a.y, c.y), 0.f);
    v.z = fmaxf(fmaf(v.z, a.z, c.z), 0.f);
    v.w = fmaxf(fmaf(v.w, a.w, c.w), 0.f);
    x[i] = v;
}

extern "C" void kernel_launch(void* const* d_in, const int* in_sizes, int n_in,
                              void* d_out, int out_size, void* d_ws, size_t ws_size,
                              hipStream_t stream) {
    const float4* feat  = (const float4*)d_in[0];  // [M,64,4] fp32
    const int*    nump  = (const int*)d_in[1];     // [M]
    // d_in[2] = coors (unused)
    const float*  W     = (const float*)d_in[3];   // [64,192]
    const float*  bvec  = (const float*)d_in[4];   // [64]
    const float*  gamma = (const float*)d_in[5];   // [64]
    const float*  beta  = (const float*)d_in[6];   // [64]

    const int M = in_sizes[1];
    float* xout   = (float*)d_out;
    float* totals = (float*)d_ws;        // [128] sum | sumsq

    hipMemsetAsync(d_ws, 0, 128 * sizeof(float), stream);

    const int nblk = (M + 4 * HROWS - 1) / (4 * HROWS);   // 64 rows/block
    k1_hist_mfma<<<nblk, 256, 0, stream>>>(feat, nump, W, bvec, xout, totals, M);

    const int n4 = out_size / 4;
    k3_bn_apply<<<(n4 + 255) / 256, 256, 0, stream>>>((float4*)d_out, totals, gamma, beta,
                                                      1.0f / (float)M, n4);
}

// Round 4
// 235.119 us; speedup vs baseline: 1.6020x; 1.0817x over previous
//
#include <hip/hip_runtime.h>
#include <hip/hip_bf16.h>
#include <math.h>

// PillarHist: per-row 64-bin hist (count/mean_z/mean_r interleaved) -> Linear(192->64) -> BN(train) -> ReLU
// k0: build permuted bf16 B-fragments into d_ws (global, L2-hot) + zero BN totals.
// k1: wave-private LDS hist (no block barriers in hot path) + MFMA with B-frags from global (double-buffered).
// k3: recompute scale/shift from totals per block + apply BN+ReLU in-place.

typedef __attribute__((ext_vector_type(8))) short bf16x8;   // 8 bf16 = 4 VGPRs = 16 B
typedef __attribute__((ext_vector_type(4))) float f32x4;

#define ZMINF   (-3.0f)
#define INV_BIN 16.0f        // 1/BIN_SIZE (exact pow2)
#define HROWS   16           // rows per wave (MFMA M)
#define HPAD    196          // hist row stride (floats); (4*col+8*quad)%32 -> only 2-way b128 aliasing

__device__ __forceinline__ short f2bf(float f) {
    __hip_bfloat16 h = __float2bfloat16(f);   // RNE
    return __builtin_bit_cast(short, h);
}

// ---- k0: one block. Permuted W -> bf16 fragments (frag-major [s*4+t][lane][j]) + zero totals ----
__global__ __launch_bounds__(256)
void k0_prep(const float* __restrict__ W,      // [64,192]
             short*       __restrict__ wsW,    // [24*64*8] bf16
             float*       __restrict__ totals) // [128]
{
    const int tid = threadIdx.x;
    for (int e = tid; e < 24 * 64 * 8; e += 256) {
        const int j  = e & 7;
        const int ln = (e >> 3) & 63;
        const int st = e >> 9;                       // s*4+t
        const int s  = st >> 2, t = st & 3;
        const int k  = s * 32 + (ln >> 4) * 8 + j;   // planar k
        const int n  = t * 16 + (ln & 15);           // output channel
        const int wc = (k < 64) ? 3 * k
                     : (k < 128) ? 3 * (k - 64) + 1
                                 : 3 * (k - 128) + 2;
        wsW[e] = f2bf(W[n * 192 + wc]);
    }
    if (tid < 128) totals[tid] = 0.f;
}

__global__ __launch_bounds__(256, 3)
void k1_hist_mfma(const float4* __restrict__ feat,   // [M,64] float4 (C=4)
                  const int*    __restrict__ nump,   // [M]
                  const bf16x8* __restrict__ wsWf,   // [24*64] B fragments (global, L2-hot)
                  const float*  __restrict__ bvec,   // [64]
                  float*        __restrict__ xout,   // [M,64] pre-BN x (d_out)
                  float*        __restrict__ totals, // [128] global atomics: sum | sumsq
                  int M)
{
    __shared__ float sH[4 * HROWS * HPAD];   // 50176 B -> 3 blocks/CU

    const int tid  = threadIdx.x;
    const int wave = tid >> 6;
    const int lane = tid & 63;
    const int col  = lane & 15;
    const int quad = lane >> 4;

    const int gbase = (blockIdx.x * 4 + wave) * HROWS;
    float* hw = &sH[wave * HROWS * HPAD];
    float psum[4] = {0.f, 0.f, 0.f, 0.f};
    float psq[4]  = {0.f, 0.f, 0.f, 0.f};

    if (gbase < M) {
        // ---- zero wave-private hist region ----
        float4* p4 = (float4*)hw;
        #pragma unroll
        for (int i = 0; i < 13; ++i) {
            const int idx = lane + i * 64;
            if (idx < (HROWS * HPAD) / 4) p4[idx] = float4{0.f, 0.f, 0.f, 0.f};
        }
        __builtin_amdgcn_wave_barrier();

        // ---- build 16 rows, 8 at a time (8 independent HBM loads in flight per batch) ----
        #pragma unroll
        for (int rb = 0; rb < HROWS; rb += 8) {
            float4 v[8]; int np[8];
            #pragma unroll
            for (int u = 0; u < 8; ++u) {
                const int row = gbase + rb + u;
                const int rc  = min(row, M - 1);        // branchless clamp; np=0 kills OOB rows
                v[u]  = feat[(size_t)rc * 64 + lane];
                np[u] = (row < M) ? nump[rc] : 0;
            }
            #pragma unroll
            for (int u = 0; u < 8; ++u) {
                if (lane < np[u]) {
                    const float z = v[u].z, rr = v[u].w;
                    int bi = (int)((z - ZMINF) * INV_BIN);  // trunc, matches astype(int32)
                    bi = min(max(bi, 0), 63);
                    float* hrow = hw + (rb + u) * HPAD;
                    atomicAdd(hrow + bi, 1.0f);
                    atomicAdd(hrow + 64 + bi, z);
                    atomicAdd(hrow + 128 + bi, rr);
                }
            }
        }
        __builtin_amdgcn_wave_barrier();
        __threadfence_block();   // drain ds_adds before fragment reads (wave-private region)

        // ---- MFMA: A from LDS (means on the fly), B from global (double-buffered regs) ----
        f32x4 acc[4] = {};
        bf16x8 bcur[4], bnxt[4];
        #pragma unroll
        for (int t = 0; t < 4; ++t) bcur[t] = wsWf[t * 64 + lane];   // s=0 frags

        const float* ar = hw + col * HPAD + quad * 8;   // A row m = col, k = quad*8+j (+32s)
        float c0[8], c1[8];
        #pragma unroll
        for (int s = 0; s < 6; ++s) {
            if (s < 5) {
                #pragma unroll
                for (int t = 0; t < 4; ++t) bnxt[t] = wsWf[((s + 1) * 4 + t) * 64 + lane];
            }
            const float4* ap = (const float4*)(ar + s * 32);
            const float4 a0 = ap[0], a1 = ap[1];
            float av[8] = {a0.x, a0.y, a0.z, a0.w, a1.x, a1.y, a1.z, a1.w};
            if (s == 0) {
                #pragma unroll
                for (int j = 0; j < 8; ++j) c0[j] = av[j];
            } else if (s == 1) {
                #pragma unroll
                for (int j = 0; j < 8; ++j) c1[j] = av[j];
            } else if (s == 2) {
                #pragma unroll
                for (int j = 0; j < 8; ++j) { c0[j] = __builtin_amdgcn_rcpf(c0[j] + 1e-5f); av[j] *= c0[j]; }
            } else if (s == 3) {
                #pragma unroll
                for (int j = 0; j < 8; ++j) { c1[j] = __builtin_amdgcn_rcpf(c1[j] + 1e-5f); av[j] *= c1[j]; }
            } else if (s == 4) {
                #pragma unroll
                for (int j = 0; j < 8; ++j) av[j] *= c0[j];
            } else {
                #pragma unroll
                for (int j = 0; j < 8; ++j) av[j] *= c1[j];
            }
            bf16x8 af;
            #pragma unroll
            for (int j = 0; j < 8; ++j) af[j] = f2bf(av[j]);
            #pragma unroll
            for (int t = 0; t < 4; ++t)
                acc[t] = __builtin_amdgcn_mfma_f32_16x16x32_bf16(af, bcur[t], acc[t], 0, 0, 0);
            #pragma unroll
            for (int t = 0; t < 4; ++t) bcur[t] = bnxt[t];
        }

        // ---- epilogue: +bias, store x, BN partials. C/D: col=lane&15, row=quad*4+i ----
        #pragma unroll
        for (int t = 0; t < 4; ++t) {
            const float bias = bvec[t * 16 + col];
            #pragma unroll
            for (int i = 0; i < 4; ++i) {
                const int row = gbase + quad * 4 + i;
                if (row < M) {
                    const float xv = acc[t][i] + bias;
                    xout[(size_t)row * 64 + t * 16 + col] = xv;
                    psum[t] += xv;
                    psq[t]  += xv * xv;
                }
            }
        }
    }

    // ---- BN partials: quad-reduce in-wave, block-reduce via LDS, one atomic set per block ----
    #pragma unroll
    for (int t = 0; t < 4; ++t) {
        psum[t] += __shfl_xor(psum[t], 16);
        psum[t] += __shfl_xor(psum[t], 32);
        psq[t]  += __shfl_xor(psq[t], 16);
        psq[t]  += __shfl_xor(psq[t], 32);
    }
    __syncthreads();   // everyone done with hist regions; reuse sH
    float* hw2 = &sH[wave * HROWS * HPAD];
    if (quad == 0) {
        #pragma unroll
        for (int t = 0; t < 4; ++t) {
            hw2[t * 16 + col]      = psum[t];
            hw2[64 + t * 16 + col] = psq[t];
        }
    }
    __syncthreads();
    if (tid < 128) {
        const float tot = sH[tid] + sH[HROWS * HPAD + tid]
                        + sH[2 * HROWS * HPAD + tid] + sH[3 * HROWS * HPAD + tid];
        atomicAdd(&totals[tid], tot);
    }
}

__global__ __launch_bounds__(256)
void k3_bn_apply(float4* __restrict__ x,
                 const float* __restrict__ totals,
                 const float* __restrict__ gamma,
                 const float* __restrict__ beta,
                 float invM, int n4)
{
    __shared__ float sa[64];
    __shared__ float sc[64];
    const int t = threadIdx.x;
    if (t < 64) {   // per-block recompute of scale/shift: 512 B L2-hot, deterministic across blocks
        const float mu   = totals[t] * invM;
        const float q    = totals[64 + t] * invM;
        const float var  = q - mu * mu;
        const float rstd = 1.0f / sqrtf(var + 1e-5f);
        const float a    = gamma[t] * rstd;
        sa[t] = a;
        sc[t] = beta[t] - mu * a;
    }
    __syncthreads();
    const int i = blockIdx.x * 256 + t;
    if (i >= n4) return;
    const float4 a = ((const float4*)sa)[i & 15];   // 64 ch = 16 float4
    const float4 c = ((const float4*)sc)[i & 15];
    float4 v = x[i];
    v.x = fmaxf(fmaf(v.x, a.x, c.x), 0.f);
    v.y = fmaxf(fmaf(v.y, a.y, c.y), 0.f);
    v.z = fmaxf(fmaf(v.z, a.z, c.z), 0.f);
    v.w = fmaxf(fmaf(v.w, a.w, c.w), 0.f);
    x[i] = v;
}

extern "C" void kernel_launch(void* const* d_in, const int* in_sizes, int n_in,
                              void* d_out, int out_size, void* d_ws, size_t ws_size,
                              hipStream_t stream) {
    const float4* feat  = (const float4*)d_in[0];  // [M,64,4] fp32
    const int*    nump  = (const int*)d_in[1];     // [M]
    // d_in[2] = coors (unused)
    const float*  W     = (const float*)d_in[3];   // [64,192]
    const float*  bvec  = (const float*)d_in[4];   // [64]
    const float*  gamma = (const float*)d_in[5];   // [64]
    const float*  beta  = (const float*)d_in[6];   // [64]

    const int M = in_sizes[1];
    float* xout   = (float*)d_out;
    short* wsW    = (short*)d_ws;                      // [24*64*8] bf16 B-fragments
    float* totals = (float*)((char*)d_ws + 24 * 64 * 8 * sizeof(short));  // [128]

    k0_prep<<<1, 256, 0, stream>>>(W, wsW, totals);

    const int nblk = (M + 4 * HROWS - 1) / (4 * HROWS);   // 64 rows/block
    k1_hist_mfma<<<nblk, 256, 0, stream>>>(feat, nump, (const bf16x8*)wsW, bvec, xout, totals, M);

    const int n4 = out_size / 4;
    k3_bn_apply<<<(n4 + 255) / 256, 256, 0, stream>>>((float4*)d_out, totals, gamma, beta,
                                                      1.0f / (float)M, n4);
}

// Round 5
// 223.299 us; speedup vs baseline: 1.6868x; 1.0529x over previous
//
#include <hip/hip_runtime.h>
#include <hip/hip_bf16.h>
#include <math.h>

// PillarHist: per-row 64-bin hist (count/mean_z/mean_r interleaved) -> Linear(192->64) -> BN(train) -> ReLU
// k0: build permuted bf16 B-fragments into d_ws + zero BN totals.
// k1: wave-private LDS hist with NATIVE INTEGER fixed-point atomics (ds_add_u32, no fp-CAS loops)
//     + MFMA with B-frags from global (double-buffered regs) + u64 fixed-point BN total atomics.
// k3: recompute scale/shift from totals per block + apply BN+ReLU in-place.

typedef __attribute__((ext_vector_type(8))) short bf16x8;   // 8 bf16 = 4 VGPRs = 16 B
typedef __attribute__((ext_vector_type(4))) float f32x4;
typedef __attribute__((ext_vector_type(4))) int   i32x4;

#define ZMINF   (-3.0f)
#define INV_BIN 16.0f            // 1/BIN_SIZE (exact pow2)
#define HROWS   16               // rows per wave (MFMA M)
#define HPAD    196              // hist row stride (ints); 16B-aligned frag reads, 2-way b128 aliasing only
#define SZF     524288.0f        // 2^19 fixed-point scale for z/r sums
#define INV_SZF (1.0f / 524288.0f)
#define TSC     16777216.0f      // 2^24 fixed-point scale for BN totals
#define INV_TSC (1.0f / 16777216.0f)

__device__ __forceinline__ short f2bf(float f) {
    __hip_bfloat16 h = __float2bfloat16(f);   // RNE
    return __builtin_bit_cast(short, h);
}

// ---- k0: one block. Permuted W -> bf16 fragments (frag-major [s*4+t][lane][j]) + zero totals ----
__global__ __launch_bounds__(256)
void k0_prep(const float* __restrict__ W,                  // [64,192]
             short*       __restrict__ wsW,                // [24*64*8] bf16
             unsigned long long* __restrict__ totals)      // [128]
{
    const int tid = threadIdx.x;
    for (int e = tid; e < 24 * 64 * 8; e += 256) {
        const int j  = e & 7;
        const int ln = (e >> 3) & 63;
        const int st = e >> 9;                       // s*4+t
        const int s  = st >> 2, t = st & 3;
        const int k  = s * 32 + (ln >> 4) * 8 + j;   // planar k
        const int n  = t * 16 + (ln & 15);           // output channel
        const int wc = (k < 64) ? 3 * k
                     : (k < 128) ? 3 * (k - 64) + 1
                                 : 3 * (k - 128) + 2;
        wsW[e] = f2bf(W[n * 192 + wc]);
    }
    if (tid < 128) totals[tid] = 0ull;
}

__global__ __launch_bounds__(256, 3)
void k1_hist_mfma(const float4* __restrict__ feat,   // [M,64] float4 (C=4)
                  const int*    __restrict__ nump,   // [M]
                  const bf16x8* __restrict__ wsWf,   // [24*64] B fragments (global, L2-hot)
                  const float*  __restrict__ bvec,   // [64]
                  float*        __restrict__ xout,   // [M,64] pre-BN x (d_out)
                  unsigned long long* __restrict__ totals, // [128] fixed-point sum | sumsq
                  int M)
{
    __shared__ int sH[4 * HROWS * HPAD];   // 50176 B -> 3 blocks/CU

    const int tid  = threadIdx.x;
    const int wave = tid >> 6;
    const int lane = tid & 63;
    const int col  = lane & 15;
    const int quad = lane >> 4;

    const int gbase = (blockIdx.x * 4 + wave) * HROWS;
    int* hw = &sH[wave * HROWS * HPAD];
    float psum[4] = {0.f, 0.f, 0.f, 0.f};
    float psq[4]  = {0.f, 0.f, 0.f, 0.f};

    if (gbase < M) {
        // ---- zero wave-private hist region ----
        i32x4* p4 = (i32x4*)hw;
        #pragma unroll
        for (int i = 0; i < 13; ++i) {
            const int idx = lane + i * 64;
            if (idx < (HROWS * HPAD) / 4) p4[idx] = i32x4{0, 0, 0, 0};
        }
        __builtin_amdgcn_wave_barrier();

        // ---- build 16 rows, 8 at a time; NATIVE ds_add_u32 atomics (fire-and-forget) ----
        #pragma unroll
        for (int rb = 0; rb < HROWS; rb += 8) {
            float4 v[8]; int np[8];
            #pragma unroll
            for (int u = 0; u < 8; ++u) {
                const int row = gbase + rb + u;
                const int rc  = min(row, M - 1);        // branchless clamp; np=0 kills OOB rows
                v[u]  = feat[(size_t)rc * 64 + lane];
                np[u] = (row < M) ? nump[rc] : 0;
            }
            #pragma unroll
            for (int u = 0; u < 8; ++u) {
                if (lane < np[u]) {
                    const float z = v[u].z, rr = v[u].w;
                    int bi = (int)((z - ZMINF) * INV_BIN);  // trunc, matches astype(int32)
                    bi = min(max(bi, 0), 63);
                    int* hrow = hw + (rb + u) * HPAD;
                    atomicAdd(hrow + bi, 1);                        // ds_add_u32
                    atomicAdd(hrow + 64 + bi, (int)(z * SZF));      // fixed-point 2^19
                    atomicAdd(hrow + 128 + bi, (int)(rr * SZF));
                }
            }
        }
        __builtin_amdgcn_wave_barrier();
        __threadfence_block();   // drain ds ops before fragment reads (wave-private region)

        // ---- MFMA: A from LDS ints (means on the fly), B from global (double-buffered regs) ----
        f32x4 acc[4] = {};
        bf16x8 bcur[4], bnxt[4];
        #pragma unroll
        for (int t = 0; t < 4; ++t) bcur[t] = wsWf[t * 64 + lane];   // s=0 frags

        const int* ar = hw + col * HPAD + quad * 8;   // A row m = col, k = quad*8+j (+32s)
        float c0[8], c1[8];
        #pragma unroll
        for (int s = 0; s < 6; ++s) {
            if (s < 5) {
                #pragma unroll
                for (int t = 0; t < 4; ++t) bnxt[t] = wsWf[((s + 1) * 4 + t) * 64 + lane];
            }
            const i32x4* ap = (const i32x4*)(ar + s * 32);
            const i32x4 a0 = ap[0], a1 = ap[1];
            const int iv[8] = {a0.x, a0.y, a0.z, a0.w, a1.x, a1.y, a1.z, a1.w};
            float av[8];
            if (s == 0) {
                #pragma unroll
                for (int j = 0; j < 8; ++j) { c0[j] = (float)iv[j]; av[j] = c0[j]; }
            } else if (s == 1) {
                #pragma unroll
                for (int j = 0; j < 8; ++j) { c1[j] = (float)iv[j]; av[j] = c1[j]; }
            } else if (s == 2) {
                #pragma unroll
                for (int j = 0; j < 8; ++j) {
                    c0[j] = __builtin_amdgcn_rcpf(c0[j] + 1e-5f) * INV_SZF;  // fold 2^-19 into rcp
                    av[j] = (float)iv[j] * c0[j];
                }
            } else if (s == 3) {
                #pragma unroll
                for (int j = 0; j < 8; ++j) {
                    c1[j] = __builtin_amdgcn_rcpf(c1[j] + 1e-5f) * INV_SZF;
                    av[j] = (float)iv[j] * c1[j];
                }
            } else if (s == 4) {
                #pragma unroll
                for (int j = 0; j < 8; ++j) av[j] = (float)iv[j] * c0[j];
            } else {
                #pragma unroll
                for (int j = 0; j < 8; ++j) av[j] = (float)iv[j] * c1[j];
            }
            bf16x8 af;
            #pragma unroll
            for (int j = 0; j < 8; ++j) af[j] = f2bf(av[j]);
            #pragma unroll
            for (int t = 0; t < 4; ++t)
                acc[t] = __builtin_amdgcn_mfma_f32_16x16x32_bf16(af, bcur[t], acc[t], 0, 0, 0);
            #pragma unroll
            for (int t = 0; t < 4; ++t) bcur[t] = bnxt[t];
        }

        // ---- epilogue: +bias, store x, BN partials. C/D: col=lane&15, row=quad*4+i ----
        #pragma unroll
        for (int t = 0; t < 4; ++t) {
            const float bias = bvec[t * 16 + col];
            #pragma unroll
            for (int i = 0; i < 4; ++i) {
                const int row = gbase + quad * 4 + i;
                if (row < M) {
                    const float xv = acc[t][i] + bias;
                    xout[(size_t)row * 64 + t * 16 + col] = xv;
                    psum[t] += xv;
                    psq[t]  += xv * xv;
                }
            }
        }
    }

    // ---- BN partials: quad-reduce in-wave, block-reduce via LDS, one u64 atomic set per block ----
    #pragma unroll
    for (int t = 0; t < 4; ++t) {
        psum[t] += __shfl_xor(psum[t], 16);
        psum[t] += __shfl_xor(psum[t], 32);
        psq[t]  += __shfl_xor(psq[t], 16);
        psq[t]  += __shfl_xor(psq[t], 32);
    }
    __syncthreads();   // everyone done with hist regions; reuse sH as float scratch
    float* sF = (float*)sH;
    float* hw2 = sF + wave * HROWS * HPAD;
    if (quad == 0) {
        #pragma unroll
        for (int t = 0; t < 4; ++t) {
            hw2[t * 16 + col]      = psum[t];
            hw2[64 + t * 16 + col] = psq[t];
        }
    }
    __syncthreads();
    if (tid < 128) {
        const float tot = sF[tid] + sF[HROWS * HPAD + tid]
                        + sF[2 * HROWS * HPAD + tid] + sF[3 * HROWS * HPAD + tid];
        // fixed-point 2^24, two's complement via i64->u64 (native global_atomic_add_x2)
        atomicAdd(&totals[tid], (unsigned long long)(long long)(tot * TSC));
    }
}

__global__ __launch_bounds__(256)
void k3_bn_apply(float4* __restrict__ x,
                 const unsigned long long* __restrict__ totals,
                 const float* __restrict__ gamma,
                 const float* __restrict__ beta,
                 float invM, int n4)
{
    __shared__ float sa[64];
    __shared__ float sc[64];
    const int t = threadIdx.x;
    if (t < 64) {   // per-block recompute of scale/shift: 1 KB L2-hot, deterministic across blocks
        const float cf   = invM * INV_TSC;
        const float mu   = (float)(long long)totals[t] * cf;
        const float q    = (float)(long long)totals[64 + t] * cf;
        const float var  = q - mu * mu;
        const float rstd = 1.0f / sqrtf(var + 1e-5f);
        const float a    = gamma[t] * rstd;
        sa[t] = a;
        sc[t] = beta[t] - mu * a;
    }
    __syncthreads();
    const int i = blockIdx.x * 256 + t;
    if (i >= n4) return;
    const float4 a = ((const float4*)sa)[i & 15];   // 64 ch = 16 float4
    const float4 c = ((const float4*)sc)[i & 15];
    float4 v = x[i];
    v.x = fmaxf(fmaf(v.x, a.x, c.x), 0.f);
    v.y = fmaxf(fmaf(v.y, a.y, c.y), 0.f);
    v.z = fmaxf(fmaf(v.z, a.z, c.z), 0.f);
    v.w = fmaxf(fmaf(v.w, a.w, c.w), 0.f);
    x[i] = v;
}

extern "C" void kernel_launch(void* const* d_in, const int* in_sizes, int n_in,
                              void* d_out, int out_size, void* d_ws, size_t ws_size,
                              hipStream_t stream) {
    const float4* feat  = (const float4*)d_in[0];  // [M,64,4] fp32
    const int*    nump  = (const int*)d_in[1];     // [M]
    // d_in[2] = coors (unused)
    const float*  W     = (const float*)d_in[3];   // [64,192]
    const float*  bvec  = (const float*)d_in[4];   // [64]
    const float*  gamma = (const float*)d_in[5];   // [64]
    const float*  beta  = (const float*)d_in[6];   // [64]

    const int M = in_sizes[1];
    float* xout = (float*)d_out;
    short* wsW  = (short*)d_ws;                                   // [24*64*8] bf16 B-fragments
    unsigned long long* totals =
        (unsigned long long*)((char*)d_ws + 24 * 64 * 8 * sizeof(short));  // [128] u64

    k0_prep<<<1, 256, 0, stream>>>(W, wsW, totals);

    const int nblk = (M + 4 * HROWS - 1) / (4 * HROWS);   // 64 rows/block
    k1_hist_mfma<<<nblk, 256, 0, stream>>>(feat, nump, (const bf16x8*)wsW, bvec, xout, totals, M);

    const int n4 = out_size / 4;
    k3_bn_apply<<<(n4 + 255) / 256, 256, 0, stream>>>((float4*)d_out, totals, gamma, beta,
                                                      1.0f / (float)M, n4);
}

// Round 6
// 206.130 us; speedup vs baseline: 1.8273x; 1.0833x over previous
//
#include <hip/hip_runtime.h>
#include <hip/hip_bf16.h>
#include <math.h>

// PillarHist: per-row 64-bin hist (count/mean_z/mean_r interleaved) -> Linear(192->64) -> BN(train) -> ReLU
// k0: build permuted bf16 B-fragments into d_ws + zero BN totals (16 replicas).
// k1: wave-private LDS hist (native ds_add_u32 fixed-point) + MFMA (B-frags from global, double-buffered)
//     + BN totals via 16-WAY REPLICATED u64 atomics (kills L2 same-address serialization / retire stall).
// k3: sum replicas per block -> scale/shift -> apply BN+ReLU in-place.

typedef __attribute__((ext_vector_type(8))) short bf16x8;   // 8 bf16 = 4 VGPRs = 16 B
typedef __attribute__((ext_vector_type(4))) float f32x4;
typedef __attribute__((ext_vector_type(4))) int   i32x4;

#define ZMINF   (-3.0f)
#define INV_BIN 16.0f            // 1/BIN_SIZE (exact pow2)
#define HROWS   16               // rows per wave (MFMA M)
#define HPAD    196              // hist row stride (ints); 2-way b128 aliasing only
#define SZF     524288.0f        // 2^19 fixed-point scale for z/r sums
#define INV_SZF (1.0f / 524288.0f)
#define TSC     16777216.0f      // 2^24 fixed-point scale for BN totals
#define INV_TSC (1.0f / 16777216.0f)
#define REPS    16               // BN total replicas (atomic contention 1563 -> ~98 per address)

__device__ __forceinline__ short f2bf(float f) {
    __hip_bfloat16 h = __float2bfloat16(f);   // RNE
    return __builtin_bit_cast(short, h);
}

// ---- k0: one block. Permuted W -> bf16 fragments (frag-major [s*4+t][lane][j]) + zero totals ----
__global__ __launch_bounds__(256)
void k0_prep(const float* __restrict__ W,                  // [64,192]
             short*       __restrict__ wsW,                // [24*64*8] bf16
             unsigned long long* __restrict__ totals)      // [REPS*128]
{
    const int tid = threadIdx.x;
    for (int e = tid; e < 24 * 64 * 8; e += 256) {
        const int j  = e & 7;
        const int ln = (e >> 3) & 63;
        const int st = e >> 9;                       // s*4+t
        const int s  = st >> 2, t = st & 3;
        const int k  = s * 32 + (ln >> 4) * 8 + j;   // planar k
        const int n  = t * 16 + (ln & 15);           // output channel
        const int wc = (k < 64) ? 3 * k
                     : (k < 128) ? 3 * (k - 64) + 1
                                 : 3 * (k - 128) + 2;
        wsW[e] = f2bf(W[n * 192 + wc]);
    }
    for (int e = tid; e < REPS * 128; e += 256) totals[e] = 0ull;
}

__global__ __launch_bounds__(256, 3)
void k1_hist_mfma(const float4* __restrict__ feat,   // [M,64] float4 (C=4)
                  const int*    __restrict__ nump,   // [M]
                  const bf16x8* __restrict__ wsWf,   // [24*64] B fragments (global, L2-hot)
                  const float*  __restrict__ bvec,   // [64]
                  float*        __restrict__ xout,   // [M,64] pre-BN x (d_out)
                  unsigned long long* __restrict__ totals, // [REPS*128] fixed-point sum | sumsq
                  int M)
{
    __shared__ int sH[4 * HROWS * HPAD];   // 50176 B -> 3 blocks/CU

    const int tid  = threadIdx.x;
    const int wave = tid >> 6;
    const int lane = tid & 63;
    const int col  = lane & 15;
    const int quad = lane >> 4;

    const int gbase = (blockIdx.x * 4 + wave) * HROWS;
    int* hw = &sH[wave * HROWS * HPAD];
    float psum[4] = {0.f, 0.f, 0.f, 0.f};
    float psq[4]  = {0.f, 0.f, 0.f, 0.f};

    if (gbase < M) {
        // ---- zero wave-private hist region ----
        i32x4* p4 = (i32x4*)hw;
        #pragma unroll
        for (int i = 0; i < 13; ++i) {
            const int idx = lane + i * 64;
            if (idx < (HROWS * HPAD) / 4) p4[idx] = i32x4{0, 0, 0, 0};
        }
        __builtin_amdgcn_wave_barrier();

        // ---- 16 rows loaded in ONE batch (single vmcnt latency round), then native ds_add_u32 ----
        float4 v[HROWS]; int np[HROWS];
        #pragma unroll
        for (int u = 0; u < HROWS; ++u) {
            const int row = gbase + u;
            const int rc  = min(row, M - 1);        // branchless clamp; np=0 kills OOB rows
            v[u]  = feat[(size_t)rc * 64 + lane];
            np[u] = (row < M) ? nump[rc] : 0;
        }
        #pragma unroll
        for (int u = 0; u < HROWS; ++u) {
            if (lane < np[u]) {
                const float z = v[u].z, rr = v[u].w;
                int bi = (int)((z - ZMINF) * INV_BIN);  // trunc, matches astype(int32)
                bi = min(max(bi, 0), 63);
                int* hrow = hw + u * HPAD;
                atomicAdd(hrow + bi, 1);                        // ds_add_u32
                atomicAdd(hrow + 64 + bi, (int)(z * SZF));      // fixed-point 2^19
                atomicAdd(hrow + 128 + bi, (int)(rr * SZF));
            }
        }
        __builtin_amdgcn_wave_barrier();
        __threadfence_block();   // drain ds ops before fragment reads (wave-private region)

        // ---- MFMA: A from LDS ints (means on the fly), B from global (double-buffered regs) ----
        f32x4 acc[4] = {};
        bf16x8 bcur[4], bnxt[4];
        #pragma unroll
        for (int t = 0; t < 4; ++t) bcur[t] = wsWf[t * 64 + lane];   // s=0 frags

        const int* ar = hw + col * HPAD + quad * 8;   // A row m = col, k = quad*8+j (+32s)
        float c0[8], c1[8];
        #pragma unroll
        for (int s = 0; s < 6; ++s) {
            if (s < 5) {
                #pragma unroll
                for (int t = 0; t < 4; ++t) bnxt[t] = wsWf[((s + 1) * 4 + t) * 64 + lane];
            }
            const i32x4* ap = (const i32x4*)(ar + s * 32);
            const i32x4 a0 = ap[0], a1 = ap[1];
            const int iv[8] = {a0.x, a0.y, a0.z, a0.w, a1.x, a1.y, a1.z, a1.w};
            float av[8];
            if (s == 0) {
                #pragma unroll
                for (int j = 0; j < 8; ++j) { c0[j] = (float)iv[j]; av[j] = c0[j]; }
            } else if (s == 1) {
                #pragma unroll
                for (int j = 0; j < 8; ++j) { c1[j] = (float)iv[j]; av[j] = c1[j]; }
            } else if (s == 2) {
                #pragma unroll
                for (int j = 0; j < 8; ++j) {
                    c0[j] = __builtin_amdgcn_rcpf(c0[j] + 1e-5f) * INV_SZF;  // fold 2^-19 into rcp
                    av[j] = (float)iv[j] * c0[j];
                }
            } else if (s == 3) {
                #pragma unroll
                for (int j = 0; j < 8; ++j) {
                    c1[j] = __builtin_amdgcn_rcpf(c1[j] + 1e-5f) * INV_SZF;
                    av[j] = (float)iv[j] * c1[j];
                }
            } else if (s == 4) {
                #pragma unroll
                for (int j = 0; j < 8; ++j) av[j] = (float)iv[j] * c0[j];
            } else {
                #pragma unroll
                for (int j = 0; j < 8; ++j) av[j] = (float)iv[j] * c1[j];
            }
            bf16x8 af;
            #pragma unroll
            for (int j = 0; j < 8; ++j) af[j] = f2bf(av[j]);
            #pragma unroll
            for (int t = 0; t < 4; ++t)
                acc[t] = __builtin_amdgcn_mfma_f32_16x16x32_bf16(af, bcur[t], acc[t], 0, 0, 0);
            #pragma unroll
            for (int t = 0; t < 4; ++t) bcur[t] = bnxt[t];
        }

        // ---- epilogue: +bias, store x, BN partials. C/D: col=lane&15, row=quad*4+i ----
        #pragma unroll
        for (int t = 0; t < 4; ++t) {
            const float bias = bvec[t * 16 + col];
            #pragma unroll
            for (int i = 0; i < 4; ++i) {
                const int row = gbase + quad * 4 + i;
                if (row < M) {
                    const float xv = acc[t][i] + bias;
                    xout[(size_t)row * 64 + t * 16 + col] = xv;
                    psum[t] += xv;
                    psq[t]  += xv * xv;
                }
            }
        }
    }

    // ---- BN partials: quad-reduce in-wave, block-reduce via LDS, replicated u64 atomics ----
    #pragma unroll
    for (int t = 0; t < 4; ++t) {
        psum[t] += __shfl_xor(psum[t], 16);
        psum[t] += __shfl_xor(psum[t], 32);
        psq[t]  += __shfl_xor(psq[t], 16);
        psq[t]  += __shfl_xor(psq[t], 32);
    }
    __syncthreads();   // everyone done with hist regions; reuse sH as float scratch
    float* sF = (float*)sH;
    float* hw2 = sF + wave * HROWS * HPAD;
    if (quad == 0) {
        #pragma unroll
        for (int t = 0; t < 4; ++t) {
            hw2[t * 16 + col]      = psum[t];
            hw2[64 + t * 16 + col] = psq[t];
        }
    }
    __syncthreads();
    if (tid < 128) {
        const float tot = sF[tid] + sF[HROWS * HPAD + tid]
                        + sF[2 * HROWS * HPAD + tid] + sF[3 * HROWS * HPAD + tid];
        // fixed-point 2^24; replica chosen by block -> ~98-way (not 1563-way) per-address contention
        unsigned long long* dst = totals + (blockIdx.x & (REPS - 1)) * 128 + tid;
        atomicAdd(dst, (unsigned long long)(long long)(tot * TSC));
    }
}

__global__ __launch_bounds__(256)
void k3_bn_apply(float4* __restrict__ x,
                 const unsigned long long* __restrict__ totals,
                 const float* __restrict__ gamma,
                 const float* __restrict__ beta,
                 float invM, int n4)
{
    __shared__ float sT[128];
    __shared__ float sa[64];
    __shared__ float sc[64];
    const int t = threadIdx.x;
    if (t < 128) {   // sum 16 replicas: 16 KB L2-hot, deterministic across blocks
        long long s = 0;
        #pragma unroll
        for (int rep = 0; rep < REPS; ++rep) s += (long long)totals[rep * 128 + t];
        sT[t] = (float)s * (invM * INV_TSC);
    }
    __syncthreads();
    if (t < 64) {
        const float mu   = sT[t];
        const float q    = sT[64 + t];
        const float var  = q - mu * mu;
        const float rstd = 1.0f / sqrtf(var + 1e-5f);
        const float a    = gamma[t] * rstd;
        sa[t] = a;
        sc[t] = beta[t] - mu * a;
    }
    __syncthreads();
    const int i = blockIdx.x * 256 + t;
    if (i >= n4) return;
    const float4 a = ((const float4*)sa)[i & 15];   // 64 ch = 16 float4
    const float4 c = ((const float4*)sc)[i & 15];
    float4 v = x[i];
    v.x = fmaxf(fmaf(v.x, a.x, c.x), 0.f);
    v.y = fmaxf(fmaf(v.y, a.y, c.y), 0.f);
    v.z = fmaxf(fmaf(v.z, a.z, c.z), 0.f);
    v.w = fmaxf(fmaf(v.w, a.w, c.w), 0.f);
    x[i] = v;
}

extern "C" void kernel_launch(void* const* d_in, const int* in_sizes, int n_in,
                              void* d_out, int out_size, void* d_ws, size_t ws_size,
                              hipStream_t stream) {
    const float4* feat  = (const float4*)d_in[0];  // [M,64,4] fp32
    const int*    nump  = (const int*)d_in[1];     // [M]
    // d_in[2] = coors (unused)
    const float*  W     = (const float*)d_in[3];   // [64,192]
    const float*  bvec  = (const float*)d_in[4];   // [64]
    const float*  gamma = (const float*)d_in[5];   // [64]
    const float*  beta  = (const float*)d_in[6];   // [64]

    const int M = in_sizes[1];
    float* xout = (float*)d_out;
    short* wsW  = (short*)d_ws;                                   // [24*64*8] bf16 B-fragments
    unsigned long long* totals =
        (unsigned long long*)((char*)d_ws + 24 * 64 * 8 * sizeof(short));  // [REPS*128] u64

    k0_prep<<<1, 256, 0, stream>>>(W, wsW, totals);

    const int nblk = (M + 4 * HROWS - 1) / (4 * HROWS);   // 64 rows/block
    k1_hist_mfma<<<nblk, 256, 0, stream>>>(feat, nump, (const bf16x8*)wsW, bvec, xout, totals, M);

    const int n4 = out_size / 4;
    k3_bn_apply<<<(n4 + 255) / 256, 256, 0, stream>>>((float4*)d_out, totals, gamma, beta,
                                                      1.0f / (float)M, n4);
}